// Round 12
// baseline (1067.847 us; speedup 1.0000x reference)
//
#include <hip/hip_runtime.h>
#include <math.h>

typedef unsigned short u16;
typedef unsigned int u32;
typedef float f32x4 __attribute__((ext_vector_type(4)));
typedef short bfrag __attribute__((ext_vector_type(8)));

#define HS 128
#define DPLANE 4096000      // EL - EH, u16 elements
#define DHB    33554304     // hbL - hbH, u16 elements (N*HS)

__device__ __forceinline__ float sigf(float x) { return 1.0f / (1.0f + __expf(-x)); }
__device__ __forceinline__ float tanhfast(float x) {
    float e = __expf(2.0f * x);
    return 1.0f - 2.0f / (e + 1.0f);
}
__device__ __forceinline__ u16 f2bf(float f) {
    u32 u = __float_as_uint(f);
    return (u16)((u + 0x7FFFu + ((u >> 16) & 1u)) >> 16);
}
__device__ __forceinline__ float bf2f(u16 h) { return __uint_as_float(((u32)h) << 16); }

template<int N> __device__ __forceinline__ void waitv() {
    asm volatile("s_waitcnt vmcnt(%0)" :: "i"(N) : "memory");
}

// B' value: rows 0-127 emb:[W_iou|W_f|W_f], 128-255 hl:[U_iou|U_f|0], 256-383 hr:[U_iou|0|U_f]
__device__ __forceinline__ float bval_int(int k, int col,
    const float* W_iou, const float* W_f, const float* U_iou, const float* U_f)
{
    if (col < 384) {
        if (k < 128) return W_iou[k * 384 + col];
        if (k < 256) return U_iou[(k - 128) * 384 + col];
        return U_iou[(k - 256) * 384 + col];
    } else if (col < 512) {
        int cc = col - 384;
        if (k < 128) return W_f[k * 128 + cc];
        if (k < 256) return U_f[(k - 128) * 128 + cc];
        return 0.0f;
    } else {
        int cc = col - 512;
        if (k < 128) return W_f[k * 128 + cc];
        if (k < 256) return 0.0f;
        return U_f[(k - 256) * 128 + cc];
    }
}

// ---------------- prep (r11 verbatim; zbf slot doubles as barrier counters) ----------------
#define TOT_INT (12 * 40 * 2 * 512)        // 491520
#define TOT_LEAF (4 * 24 * 2 * 512)        // 98304
#define ZBF_OFF (TOT_INT + TOT_LEAF)       // 589824
#define EPL_OFF (ZBF_OFF + 128)            // 589952
#define TOT_E 4096000
#define ZBP_OFF (EPL_OFF + TOT_E)          // 4685952
#define PREP_ALL (ZBP_OFF + 128)           // 4686080

__global__ __launch_bounds__(256) void prep_kernel(
    const float* __restrict__ W_iou, const float* __restrict__ W_f,
    const float* __restrict__ U_iou, const float* __restrict__ U_f,
    const float* __restrict__ E,
    u16* __restrict__ Bint, u16* __restrict__ Bleaf,
    u16* __restrict__ EH, u16* __restrict__ EL,
    u16* __restrict__ zbp, float* __restrict__ zbf)
{
    int idx = blockIdx.x * 256 + threadIdx.x;
    if (idx < TOT_INT) {
        int j8 = idx & 7, l = (idx >> 3) & 63, half = (idx >> 9) & 1;
        int rest = idx >> 10;
        int cfabs = rest % 40, kc = rest / 40;
        int wq = cfabs / 5, g = cfabs % 5;
        int j = 16 * wq + (l & 15);
        int origcol = (g < 3) ? g * 128 + j : ((g == 3) ? 384 + j : 512 + j);
        int k = kc * 32 + (l >> 4) * 8 + j8;
        float v = bval_int(k, origcol, W_iou, W_f, U_iou, U_f);
        u16 hi = f2bf(v);
        Bint[idx] = half ? f2bf(v - bf2f(hi)) : hi;
    } else if (idx < TOT_INT + TOT_LEAF) {
        int i2 = idx - TOT_INT;
        int j8 = i2 & 7, l = (i2 >> 3) & 63, half = (i2 >> 9) & 1;
        int rest = i2 >> 10;
        int cfabs = rest % 24, kc = rest / 24;
        int wq = cfabs / 3, g = cfabs % 3;
        int origcol = g * 128 + 16 * wq + (l & 15);
        int k = kc * 32 + (l >> 4) * 8 + j8;
        float v = W_iou[k * 384 + origcol];
        u16 hi = f2bf(v);
        Bleaf[i2] = half ? f2bf(v - bf2f(hi)) : hi;
    } else if (idx < EPL_OFF) {
        zbf[idx - ZBF_OFF] = 0.0f;     // also zeroes the grid-barrier counters
    } else if (idx < ZBP_OFF) {
        int i3 = idx - EPL_OFF;
        float v = E[i3];
        u16 hi = f2bf(v);
        EH[i3] = hi;
        EL[i3] = f2bf(v - bf2f(hi));
    } else if (idx < PREP_ALL) {
        zbp[idx - ZBP_OFF] = 0;
    }
}

// ---------------- one 64-row GEMM phase, B-prefetch pipelined (r11 verbatim) ----------------
template<int NKC, int NCFA, int NCF, int MODE>
__device__ __forceinline__ void phase_gemm(
    f32x4 (&acc)[4][NCF],
    const int* __restrict__ x, const int* __restrict__ mask,
    const u16* __restrict__ EH, const u16* __restrict__ zbp,
    const u16* __restrict__ hbH,
    const u16* __restrict__ Bg,
    u16* ldsA, const u16* ldsP,
    int n0, int lastn, int t)
{
    constexpr int NB = 2 * NCF;
    const int l = t & 63, wq = t >> 6;
    const int lr = l & 15, lg = l >> 4;

    const u16 *ebp, *hb1p = nullptr, *hb2p = nullptr;
    {
        const int prow = t & 63, pk8 = ((t >> 6) & 3) * 8, pp = t >> 8;
        int ns = n0 + prow; if (ns >= lastn) ns = n0;
        const u16* Ep = pp ? (EH + DPLANE) : EH;
        ebp = (mask[ns] ? Ep + (size_t)x[ns] * HS : zbp) + pk8;
        if (MODE == 1) {
            const u16* hbp = pp ? (hbH + DHB) : hbH;
            hb1p = hbp + (size_t)(2 * ns + 1) * HS + pk8;
            hb2p = hbp + (size_t)(2 * ns + 2) * HS + pk8;
        }
    }
    auto stageA = [&](int kc, int buf) {
        const u16* src;
        if (MODE == 1) {
            int seg = kc >> 2, ks = kc & 3;
            src = (seg == 0 ? ebp : (seg == 1 ? hb1p : hb2p)) + ks * 32;
        } else {
            src = ebp + (kc & 3) * 32;
        }
        __builtin_amdgcn_global_load_lds(
            (const __attribute__((address_space(1))) void*)src,
            (__attribute__((address_space(3))) void*)(ldsA + buf * 4096 + t * 8), 16, 0, 0);
    };
    const u16* bbase = Bg + (size_t)(wq * NCF) * 1024 + (size_t)l * 8;
    auto loadB = [&](int kc, bfrag (&bh)[NCF], bfrag (&bl)[NCF]) {
        const u16* bp = bbase + (size_t)kc * ((size_t)NCFA * 1024);
#pragma unroll
        for (int cf = 0; cf < NCF; ++cf) {
            bh[cf] = *(const bfrag*)(bp + (size_t)cf * 1024);
            bl[cf] = *(const bfrag*)(bp + (size_t)cf * 1024 + 512);
        }
    };
    auto compute = [&](int kk, bfrag (&bh)[NCF], bfrag (&bl)[NCF]) {
        bfrag ah[4], al[4];
        if (MODE == 2 && kk >= 4) {
            const int seg = (kk - 4) >> 2;
            const int kk8 = ((kk - 4) & 3) * 4 + lg;
#pragma unroll
            for (int rf = 0; rf < 4; ++rf) {
                int arow = 16 * rf + lr;
                ah[rf] = *(const bfrag*)(ldsP + ((size_t)kk8 * 128 + seg * 64 + arow) * 8);
                al[rf] = *(const bfrag*)(ldsP + ((size_t)(16 + kk8) * 128 + seg * 64 + arow) * 8);
            }
        } else {
            const u16* ab = ldsA + (kk % 3) * 4096;
#pragma unroll
            for (int rf = 0; rf < 4; ++rf) {
                int arow = 16 * rf + lr;
                ah[rf] = *(const bfrag*)(ab + ((size_t)lg * 64 + arow) * 8);
                al[rf] = *(const bfrag*)(ab + ((size_t)(4 + lg) * 64 + arow) * 8);
            }
        }
#pragma unroll
        for (int cf = 0; cf < NCF; ++cf) {
#pragma unroll
            for (int rf = 0; rf < 4; ++rf)
                acc[rf][cf] = __builtin_amdgcn_mfma_f32_16x16x32_bf16(ah[rf], bh[cf], acc[rf][cf], 0, 0, 0);
#pragma unroll
            for (int rf = 0; rf < 4; ++rf)
                acc[rf][cf] = __builtin_amdgcn_mfma_f32_16x16x32_bf16(al[rf], bh[cf], acc[rf][cf], 0, 0, 0);
#pragma unroll
            for (int rf = 0; rf < 4; ++rf)
                acc[rf][cf] = __builtin_amdgcn_mfma_f32_16x16x32_bf16(ah[rf], bl[cf], acc[rf][cf], 0, 0, 0);
        }
    };

    bfrag bhA[NCF], blA[NCF], bhB[NCF], blB[NCF];
    stageA(0, 0);
    loadB(0, bhA, blA);
    stageA(1, 1);

#pragma unroll 1
    for (int kc = 0; kc < NKC; kc += 2) {
        loadB(kc + 1, bhB, blB);
        if constexpr (MODE == 2) { if (kc <= 2) waitv<NB + 1>(); else waitv<NB>(); }
        else waitv<NB + 1>();
        __builtin_amdgcn_s_barrier();
        asm volatile("" ::: "memory");
        if constexpr (MODE == 2) { if (kc + 2 < 4) stageA(kc + 2, (kc + 2) % 3); }
        else                     { if (kc + 2 <= NKC - 1) stageA(kc + 2, (kc + 2) % 3); }
        compute(kc, bhA, blA);

        { int kn = kc + 2; if (kn > NKC - 1) kn = NKC - 1; loadB(kn, bhA, blA); }
        if constexpr (MODE == 2) { if (kc == 0) waitv<NB + 1>(); else waitv<NB>(); }
        else { if (kc == NKC - 2) waitv<NB>(); else waitv<NB + 1>(); }
        __builtin_amdgcn_s_barrier();
        asm volatile("" ::: "memory");
        if constexpr (MODE == 2) { if (kc + 3 < 4) stageA(kc + 3, (kc + 3) % 3); }
        else                     { if (kc + 3 <= NKC - 1) stageA(kc + 3, (kc + 3) % 3); }
        compute(kc + 1, bhB, blB);
    }
}

// ---------------- child epilogue (r11 verbatim) ----------------
template<int NCF, bool LEAF>
__device__ __forceinline__ void child_epilogue(
    f32x4 (&acc)[4][NCF],
    const int* __restrict__ mask,
    const float* __restrict__ b_iou_x, const float* __restrict__ b_f_x,
    const float* __restrict__ b_iou_h, const float* __restrict__ b_f_h,
    float* __restrict__ h, const float* __restrict__ c,
    u16* ldsP, float* ldsC,
    int n0, int lastn, int oBase, int t)
{
    const int l = t & 63, wq = t >> 6, lr = l & 15, lg = l >> 4;
    const int j = 16 * wq + lr;
    float bix = b_iou_x[j], box = b_iou_x[HS + j], bux = b_iou_x[2 * HS + j];
    float bih = b_iou_h[j], boh = b_iou_h[HS + j], buh = b_iou_h[2 * HS + j];
    float bfx = 0.0f, bfh = 0.0f;
    if constexpr (!LEAF) { bfx = b_f_x[j]; bfh = b_f_h[j]; }
#pragma unroll
    for (int rf = 0; rf < 4; ++rf) {
#pragma unroll
        for (int r = 0; r < 4; ++r) {
            int ctr = 16 * rf + 4 * lg + r;
            int n = n0 + ctr;
            if (n >= lastn) continue;
            float m = (float)mask[n];
            float iv = acc[rf][0][r] + m * bix + bih;
            float ov = acc[rf][1][r] + m * box + boh;
            float uv = acc[rf][2][r] + m * bux + buh;
            float cn;
            if constexpr (!LEAF) {
                float fl = acc[rf][3][r] + m * bfx + bfh;
                float fr = acc[rf][4][r] + m * bfx + bfh;
                float cl = c[(size_t)(2 * n + 1) * HS + j];
                float cr = c[(size_t)(2 * n + 2) * HS + j];
                cn = sigf(iv) * tanhfast(uv) + sigf(fl) * cl + sigf(fr) * cr;
            } else {
                cn = sigf(iv) * tanhfast(uv);
            }
            float hn = sigf(ov) * tanhfast(cn);
            h[(size_t)n * HS + j] = hn;
            int o = oBase + ctr;
            int half = o & 1, slot = o >> 1;
            u16 hh = f2bf(hn);
            ldsP[((size_t)(j >> 3) * 128 + half * 64 + slot) * 8 + (j & 7)] = hh;
            ldsP[((size_t)(16 + (j >> 3)) * 128 + half * 64 + slot) * 8 + (j & 7)] = f2bf(hn - bf2f(hh));
            ldsC[o * 129 + j] = cn;
        }
    }
}

// ---------------- parent epilogue (r11 verbatim) ----------------
__device__ __forceinline__ void parent_epilogue(
    f32x4 (&acc)[4][5],
    const int* __restrict__ mask,
    const float* __restrict__ b_iou_x, const float* __restrict__ b_f_x,
    const float* __restrict__ b_iou_h, const float* __restrict__ b_f_h,
    float* __restrict__ h, float* __restrict__ c, u16* __restrict__ hbH,
    const float* ldsC,
    int n0, int lastn, int t)
{
    u16* hbL = hbH + DHB;
    const int l = t & 63, wq = t >> 6, lr = l & 15, lg = l >> 4;
    const int j = 16 * wq + lr;
    float bix = b_iou_x[j], box = b_iou_x[HS + j], bux = b_iou_x[2 * HS + j];
    float bih = b_iou_h[j], boh = b_iou_h[HS + j], buh = b_iou_h[2 * HS + j];
    float bfx = b_f_x[j], bfh = b_f_h[j];
#pragma unroll
    for (int rf = 0; rf < 4; ++rf) {
#pragma unroll
        for (int r = 0; r < 4; ++r) {
            int ctr = 16 * rf + 4 * lg + r;
            int n = n0 + ctr;
            if (n >= lastn) continue;
            float m = (float)mask[n];
            float iv = acc[rf][0][r] + m * bix + bih;
            float ov = acc[rf][1][r] + m * box + boh;
            float uv = acc[rf][2][r] + m * bux + buh;
            float fl = acc[rf][3][r] + m * bfx + bfh;
            float fr = acc[rf][4][r] + m * bfx + bfh;
            float cl = ldsC[(2 * ctr) * 129 + j];
            float cr = ldsC[(2 * ctr + 1) * 129 + j];
            float cn = sigf(iv) * tanhfast(uv) + sigf(fl) * cl + sigf(fr) * cr;
            float hn = sigf(ov) * tanhfast(cn);
            c[(size_t)n * HS + j] = cn;
            h[(size_t)n * HS + j] = hn;
            u16 hh = f2bf(hn);
            hbH[(size_t)n * HS + j] = hh;
            hbL[(size_t)n * HS + j] = f2bf(hn - bf2f(hh));
        }
    }
}

// ---------------- fused (parent, child) level-pair kernel (r11 verbatim) ----------------
template<bool LEAFCH>
__global__ __launch_bounds__(512, 2) void fused_pair(
    const int* __restrict__ x, const int* __restrict__ mask,
    const u16* __restrict__ EH, const u16* __restrict__ zbp,
    const u16* __restrict__ Bint, const u16* __restrict__ Bleaf,
    const float* __restrict__ b_iou_x, const float* __restrict__ b_f_x,
    const float* __restrict__ b_iou_h, const float* __restrict__ b_f_h,
    float* __restrict__ h, float* __restrict__ c, u16* __restrict__ hbH,
    int s0p, int Mp)
{
    __shared__ __align__(16) u16 ldsA[3 * 4096];
    __shared__ __align__(16) u16 ldsP[2 * 16 * 128 * 8];
    __shared__ __align__(16) float ldsC[128 * 129];
    const int t = threadIdx.x;
    const int p0 = s0p + blockIdx.x * 64;
    const int lastp = s0p + Mp;
    const int lastc = 2 * lastp + 1;

    constexpr int CNCF = LEAFCH ? 3 : 5;
    const f32x4 zzz = {0.0f, 0.0f, 0.0f, 0.0f};

    {
        f32x4 acc[4][CNCF];
#pragma unroll
        for (int rf = 0; rf < 4; ++rf)
#pragma unroll
            for (int cf = 0; cf < CNCF; ++cf) acc[rf][cf] = zzz;
        phase_gemm<LEAFCH ? 4 : 12, LEAFCH ? 24 : 40, CNCF, LEAFCH ? 0 : 1>(
            acc, x, mask, EH, zbp, hbH, LEAFCH ? Bleaf : Bint, ldsA, ldsP, 2 * p0 + 1, lastc, t);
        child_epilogue<CNCF, LEAFCH>(acc, mask, b_iou_x, b_f_x, b_iou_h, b_f_h,
                                     h, c, ldsP, ldsC, 2 * p0 + 1, lastc, 0, t);
    }
    __syncthreads();
    {
        f32x4 acc[4][CNCF];
#pragma unroll
        for (int rf = 0; rf < 4; ++rf)
#pragma unroll
            for (int cf = 0; cf < CNCF; ++cf) acc[rf][cf] = zzz;
        phase_gemm<LEAFCH ? 4 : 12, LEAFCH ? 24 : 40, CNCF, LEAFCH ? 0 : 1>(
            acc, x, mask, EH, zbp, hbH, LEAFCH ? Bleaf : Bint, ldsA, ldsP, 2 * p0 + 65, lastc, t);
        child_epilogue<CNCF, LEAFCH>(acc, mask, b_iou_x, b_f_x, b_iou_h, b_f_h,
                                     h, c, ldsP, ldsC, 2 * p0 + 65, lastc, 64, t);
    }
    __syncthreads();
    {
        f32x4 acc[4][5];
#pragma unroll
        for (int rf = 0; rf < 4; ++rf)
#pragma unroll
            for (int cf = 0; cf < 5; ++cf) acc[rf][cf] = zzz;
        phase_gemm<12, 40, 5, 2>(acc, x, mask, EH, zbp, hbH, Bint, ldsA, ldsP, p0, lastp, t);
        parent_epilogue(acc, mask, b_iou_x, b_f_x, b_iou_h, b_f_h,
                        h, c, hbH, ldsC, p0, lastp, t);
    }
}

// ---------------- persistent tail kernel: levels 11..0 ----------------
// Grid: 40 blocks = 8 column-groups (wq) x 5 row-groups (rg).
// B: 120KB LDS-resident (preloaded once).  A: per-lane direct plane loads into
// 24 registers per tile (all issued up-front; compiler-counted waitcnts) —
// NO barriers and NO LDS staging inside a tile.  Grid barrier between levels.
#define TAIL_BLOCKS 40

__device__ __forceinline__ void grid_barrier(u32* ctr, u32 target, int t) {
    __syncthreads();
    if (t == 0) {
        __threadfence();
        __hip_atomic_fetch_add(ctr, 1u, __ATOMIC_RELEASE, __HIP_MEMORY_SCOPE_AGENT);
        while (__hip_atomic_load(ctr, __ATOMIC_ACQUIRE, __HIP_MEMORY_SCOPE_AGENT) < target)
            __builtin_amdgcn_s_sleep(4);
        __threadfence();
    }
    __syncthreads();
}

__global__ __launch_bounds__(512, 2) void tail_kernel(
    const int* __restrict__ x, const int* __restrict__ mask,
    const u16* __restrict__ EH, const u16* __restrict__ zbp,
    const u16* __restrict__ Bint,
    const float* __restrict__ b_iou_x, const float* __restrict__ b_f_x,
    const float* __restrict__ b_iou_h, const float* __restrict__ b_f_h,
    float* __restrict__ h, float* __restrict__ c, u16* __restrict__ hbH,
    u32* __restrict__ bar)
{
    __shared__ __align__(16) u16 ldsB[120 * 512];   // 120 KB: B slice for wq
    const int t = threadIdx.x;
    const int wq = blockIdx.x & 7;
    const int rg = blockIdx.x >> 3;        // 0..4
    const int l = t & 63, w = t >> 6;
    const int lr = l & 15, lg = l >> 4;
    u16* hbL = hbH + DHB;

    // ---- one-time B preload: 120 segments of 1KB ----
    for (int rr = 0; rr < 15; ++rr) {
        int s = rr * 8 + w;                          // 0..119
        int kcq = s / 10, rem = s % 10, cf = rem >> 1, half = rem & 1;
        const u16* src = Bint + ((size_t)((kcq * 40 + wq * 5 + cf) * 2 + half)) * 512 + l * 8;
        *(bfrag*)(ldsB + (size_t)s * 512 + l * 8) = *(const bfrag*)src;
    }
    __syncthreads();

    // per-lane output column (fixed for whole kernel)
    const int j = 16 * wq + lr;
    const float bix = b_iou_x[j], box = b_iou_x[HS + j], bux = b_iou_x[2 * HS + j];
    const float bih = b_iou_h[j], boh = b_iou_h[HS + j], buh = b_iou_h[2 * HS + j];
    const float bfx = b_f_x[j], bfh = b_f_h[j];

    const f32x4 zzz = {0.0f, 0.0f, 0.0f, 0.0f};

#pragma unroll 1
    for (int lvl = 11; lvl >= 0; --lvl) {
        const int s0 = (1 << lvl) - 1, M = 1 << lvl;
        const int lastn = s0 + M;
        const int ntiles = (M + 127) >> 7;
#pragma unroll 1
        for (int tile = rg; tile < ntiles; tile += 5) {
            const int n0 = s0 + tile * 128;
            // lane (lr,lg) owns A row rowA = n0 + 16w + lr, k-slice lg*8..+8 per kc
            int rowA = n0 + 16 * w + lr;
            if (rowA >= lastn) rowA = n0;
            const int mk = mask[rowA];
            const u16* pE = (mk ? EH + (size_t)x[rowA] * HS : zbp) + lg * 8;
            const int dE = mk ? DPLANE : 0;
            const u16* p1 = hbH + (size_t)(2 * rowA + 1) * HS + lg * 8;
            const u16* p2 = hbH + (size_t)(2 * rowA + 2) * HS + lg * 8;

            // ---- issue ALL A-fragment loads up-front (24 x 16B, register-resident) ----
            bfrag ah[12], al[12];
#pragma unroll
            for (int kc = 0; kc < 4; ++kc) {
                ah[kc] = *(const bfrag*)(pE + kc * 32);
                al[kc] = *(const bfrag*)(pE + kc * 32 + dE);
            }
#pragma unroll
            for (int kc = 0; kc < 4; ++kc) {
                ah[4 + kc] = *(const bfrag*)(p1 + kc * 32);
                al[4 + kc] = *(const bfrag*)(p1 + kc * 32 + DHB);
            }
#pragma unroll
            for (int kc = 0; kc < 4; ++kc) {
                ah[8 + kc] = *(const bfrag*)(p2 + kc * 32);
                al[8 + kc] = *(const bfrag*)(p2 + kc * 32 + DHB);
            }

            f32x4 acc[5];
#pragma unroll
            for (int cf = 0; cf < 5; ++cf) acc[cf] = zzz;

#pragma unroll
            for (int kc = 0; kc < 12; ++kc) {
                const u16* bb = ldsB + (size_t)kc * (10 * 512) + l * 8;
#pragma unroll
                for (int cf = 0; cf < 5; ++cf) {
                    bfrag bh = *(const bfrag*)(bb + (size_t)(2 * cf) * 512);
                    bfrag bl = *(const bfrag*)(bb + (size_t)(2 * cf + 1) * 512);
                    acc[cf] = __builtin_amdgcn_mfma_f32_16x16x32_bf16(ah[kc], bh, acc[cf], 0, 0, 0);
                    acc[cf] = __builtin_amdgcn_mfma_f32_16x16x32_bf16(al[kc], bh, acc[cf], 0, 0, 0);
                    acc[cf] = __builtin_amdgcn_mfma_f32_16x16x32_bf16(ah[kc], bl, acc[cf], 0, 0, 0);
                }
            }

            // ---- epilogue: rows n0 + 16w + 4lg + r, column j ----
#pragma unroll
            for (int r = 0; r < 4; ++r) {
                int n = n0 + 16 * w + 4 * lg + r;
                if (n >= lastn) continue;
                float m = (float)mask[n];
                float iv = acc[0][r] + m * bix + bih;
                float ov = acc[1][r] + m * box + boh;
                float uv = acc[2][r] + m * bux + buh;
                float fl = acc[3][r] + m * bfx + bfh;
                float fr = acc[4][r] + m * bfx + bfh;
                float cl = c[(size_t)(2 * n + 1) * HS + j];
                float cr = c[(size_t)(2 * n + 2) * HS + j];
                float cn = sigf(iv) * tanhfast(uv) + sigf(fl) * cl + sigf(fr) * cr;
                float hn = sigf(ov) * tanhfast(cn);
                c[(size_t)n * HS + j] = cn;
                h[(size_t)n * HS + j] = hn;
                u16 hh = f2bf(hn);
                hbH[(size_t)n * HS + j] = hh;
                hbL[(size_t)n * HS + j] = f2bf(hn - bf2f(hh));
            }
        }
        if (lvl > 0) grid_barrier(&bar[11 - lvl], TAIL_BLOCKS, t);
    }
}

extern "C" void kernel_launch(void* const* d_in, const int* in_sizes, int n_in,
                              void* d_out, int out_size, void* d_ws, size_t ws_size,
                              hipStream_t stream)
{
    const int*   x       = (const int*)d_in[0];
    const int*   mask    = (const int*)d_in[1];
    const float* E       = (const float*)d_in[2];
    const float* W_iou   = (const float*)d_in[3];
    const float* b_iou_x = (const float*)d_in[4];
    const float* W_f     = (const float*)d_in[5];
    const float* b_f_x   = (const float*)d_in[6];
    const float* U_iou   = (const float*)d_in[7];
    const float* b_iou_h = (const float*)d_in[8];
    const float* U_f     = (const float*)d_in[9];
    const float* b_f_h   = (const float*)d_in[10];

    float* h = (float*)d_out;
    char* ws = (char*)d_ws;

    u16*   Bint  = (u16*)(ws);                      // 983,040
    u16*   Bleaf = (u16*)(ws + 983040);             // 196,608 -> 1,179,648
    float* zbf   = (float*)(ws + 1179648);          // 512     -> 1,180,160 (barrier ctrs live here)
    u32*   bar   = (u32*)(ws + 1179648);            // zeroed by prep each launch
    u16*   EH    = (u16*)(ws + 1180160);            // 8,192,000  -> 9,372,160
    u16*   EL    = (u16*)(ws + 9372160);            // 8,192,000  -> 17,564,160 (EH + DPLANE)
    u16*   zbp   = (u16*)(ws + 17564160);           // 256        -> 17,564,416
    float* c     = (float*)(ws + 17564416);         // 134,217,216 -> 151,781,632
    u16*   hbH   = (u16*)(ws + 151781632);          // 2 x 67,108,608 -> 285,998,848 (hbL = hbH + DHB)

    prep_kernel<<<PREP_ALL / 256, 256, 0, stream>>>(
        W_iou, W_f, U_iou, U_f, E, Bint, Bleaf, EH, EL, zbp, zbf);

    // fused (parent, child) pairs for the big levels: (16,17), (14,15), (12,13)
    for (int lvl = 16; lvl >= 12; lvl -= 2) {
        int s0p = (1 << lvl) - 1, Mp = 1 << lvl;
        int blocks = (Mp + 63) / 64;
        if (lvl == 16)
            fused_pair<true><<<blocks, 512, 0, stream>>>(
                x, mask, EH, zbp, Bint, Bleaf,
                b_iou_x, b_f_x, b_iou_h, b_f_h, h, c, hbH, s0p, Mp);
        else
            fused_pair<false><<<blocks, 512, 0, stream>>>(
                x, mask, EH, zbp, Bint, Bleaf,
                b_iou_x, b_f_x, b_iou_h, b_f_h, h, c, hbH, s0p, Mp);
    }

    // persistent tail: levels 11..0, B LDS-resident, barrier-free tiles
    tail_kernel<<<TAIL_BLOCKS, 512, 0, stream>>>(
        x, mask, EH, zbp, Bint,
        b_iou_x, b_f_x, b_iou_h, b_f_h, h, c, hbH, bar);
}

// Round 13
// 1051.905 us; speedup vs baseline: 1.0152x; 1.0152x over previous
//
#include <hip/hip_runtime.h>
#include <math.h>

typedef unsigned short u16;
typedef unsigned int u32;
typedef float f32x4 __attribute__((ext_vector_type(4)));
typedef short bfrag __attribute__((ext_vector_type(8)));

#define HS 128
#define DPLANE 4096000      // EL - EH, u16 elements
#define DHB    33554304     // hbL - hbH, u16 elements (N*HS)

__device__ __forceinline__ float sigf(float x) { return 1.0f / (1.0f + __expf(-x)); }
__device__ __forceinline__ float tanhfast(float x) {
    float e = __expf(2.0f * x);
    return 1.0f - 2.0f / (e + 1.0f);
}
__device__ __forceinline__ u16 f2bf(float f) {
    u32 u = __float_as_uint(f);
    return (u16)((u + 0x7FFFu + ((u >> 16) & 1u)) >> 16);
}
__device__ __forceinline__ float bf2f(u16 h) { return __uint_as_float(((u32)h) << 16); }

template<int N> __device__ __forceinline__ void waitv() {
    asm volatile("s_waitcnt vmcnt(%0)" :: "i"(N) : "memory");
}

// B' value: rows 0-127 emb:[W_iou|W_f|W_f], 128-255 hl:[U_iou|U_f|0], 256-383 hr:[U_iou|0|U_f]
__device__ __forceinline__ float bval_int(int k, int col,
    const float* W_iou, const float* W_f, const float* U_iou, const float* U_f)
{
    if (col < 384) {
        if (k < 128) return W_iou[k * 384 + col];
        if (k < 256) return U_iou[(k - 128) * 384 + col];
        return U_iou[(k - 256) * 384 + col];
    } else if (col < 512) {
        int cc = col - 384;
        if (k < 128) return W_f[k * 128 + cc];
        if (k < 256) return U_f[(k - 128) * 128 + cc];
        return 0.0f;
    } else {
        int cc = col - 512;
        if (k < 128) return W_f[k * 128 + cc];
        if (k < 256) return 0.0f;
        return U_f[(k - 256) * 128 + cc];
    }
}

// ---------------- prep (r11 verbatim; zbf slot doubles as barrier counters) ----------------
#define TOT_INT (12 * 40 * 2 * 512)        // 491520
#define TOT_LEAF (4 * 24 * 2 * 512)        // 98304
#define ZBF_OFF (TOT_INT + TOT_LEAF)       // 589824
#define EPL_OFF (ZBF_OFF + 128)            // 589952
#define TOT_E 4096000
#define ZBP_OFF (EPL_OFF + TOT_E)          // 4685952
#define PREP_ALL (ZBP_OFF + 128)           // 4686080

__global__ __launch_bounds__(256) void prep_kernel(
    const float* __restrict__ W_iou, const float* __restrict__ W_f,
    const float* __restrict__ U_iou, const float* __restrict__ U_f,
    const float* __restrict__ E,
    u16* __restrict__ Bint, u16* __restrict__ Bleaf,
    u16* __restrict__ EH, u16* __restrict__ EL,
    u16* __restrict__ zbp, float* __restrict__ zbf)
{
    int idx = blockIdx.x * 256 + threadIdx.x;
    if (idx < TOT_INT) {
        int j8 = idx & 7, l = (idx >> 3) & 63, half = (idx >> 9) & 1;
        int rest = idx >> 10;
        int cfabs = rest % 40, kc = rest / 40;
        int wq = cfabs / 5, g = cfabs % 5;
        int j = 16 * wq + (l & 15);
        int origcol = (g < 3) ? g * 128 + j : ((g == 3) ? 384 + j : 512 + j);
        int k = kc * 32 + (l >> 4) * 8 + j8;
        float v = bval_int(k, origcol, W_iou, W_f, U_iou, U_f);
        u16 hi = f2bf(v);
        Bint[idx] = half ? f2bf(v - bf2f(hi)) : hi;
    } else if (idx < TOT_INT + TOT_LEAF) {
        int i2 = idx - TOT_INT;
        int j8 = i2 & 7, l = (i2 >> 3) & 63, half = (i2 >> 9) & 1;
        int rest = i2 >> 10;
        int cfabs = rest % 24, kc = rest / 24;
        int wq = cfabs / 3, g = cfabs % 3;
        int origcol = g * 128 + 16 * wq + (l & 15);
        int k = kc * 32 + (l >> 4) * 8 + j8;
        float v = W_iou[k * 384 + origcol];
        u16 hi = f2bf(v);
        Bleaf[i2] = half ? f2bf(v - bf2f(hi)) : hi;
    } else if (idx < EPL_OFF) {
        zbf[idx - ZBF_OFF] = 0.0f;     // also zeroes the grid-barrier counters
    } else if (idx < ZBP_OFF) {
        int i3 = idx - EPL_OFF;
        float v = E[i3];
        u16 hi = f2bf(v);
        EH[i3] = hi;
        EL[i3] = f2bf(v - bf2f(hi));
    } else if (idx < PREP_ALL) {
        zbp[idx - ZBP_OFF] = 0;
    }
}

// ---------------- one 64-row GEMM phase, B-prefetch pipelined (r11 verbatim) ----------------
template<int NKC, int NCFA, int NCF, int MODE>
__device__ __forceinline__ void phase_gemm(
    f32x4 (&acc)[4][NCF],
    const int* __restrict__ x, const int* __restrict__ mask,
    const u16* __restrict__ EH, const u16* __restrict__ zbp,
    const u16* __restrict__ hbH,
    const u16* __restrict__ Bg,
    u16* ldsA, const u16* ldsP,
    int n0, int lastn, int t)
{
    constexpr int NB = 2 * NCF;
    const int l = t & 63, wq = t >> 6;
    const int lr = l & 15, lg = l >> 4;

    const u16 *ebp, *hb1p = nullptr, *hb2p = nullptr;
    {
        const int prow = t & 63, pk8 = ((t >> 6) & 3) * 8, pp = t >> 8;
        int ns = n0 + prow; if (ns >= lastn) ns = n0;
        const u16* Ep = pp ? (EH + DPLANE) : EH;
        ebp = (mask[ns] ? Ep + (size_t)x[ns] * HS : zbp) + pk8;
        if (MODE == 1) {
            const u16* hbp = pp ? (hbH + DHB) : hbH;
            hb1p = hbp + (size_t)(2 * ns + 1) * HS + pk8;
            hb2p = hbp + (size_t)(2 * ns + 2) * HS + pk8;
        }
    }
    auto stageA = [&](int kc, int buf) {
        const u16* src;
        if (MODE == 1) {
            int seg = kc >> 2, ks = kc & 3;
            src = (seg == 0 ? ebp : (seg == 1 ? hb1p : hb2p)) + ks * 32;
        } else {
            src = ebp + (kc & 3) * 32;
        }
        __builtin_amdgcn_global_load_lds(
            (const __attribute__((address_space(1))) void*)src,
            (__attribute__((address_space(3))) void*)(ldsA + buf * 4096 + t * 8), 16, 0, 0);
    };
    const u16* bbase = Bg + (size_t)(wq * NCF) * 1024 + (size_t)l * 8;
    auto loadB = [&](int kc, bfrag (&bh)[NCF], bfrag (&bl)[NCF]) {
        const u16* bp = bbase + (size_t)kc * ((size_t)NCFA * 1024);
#pragma unroll
        for (int cf = 0; cf < NCF; ++cf) {
            bh[cf] = *(const bfrag*)(bp + (size_t)cf * 1024);
            bl[cf] = *(const bfrag*)(bp + (size_t)cf * 1024 + 512);
        }
    };
    auto compute = [&](int kk, bfrag (&bh)[NCF], bfrag (&bl)[NCF]) {
        bfrag ah[4], al[4];
        if (MODE == 2 && kk >= 4) {
            const int seg = (kk - 4) >> 2;
            const int kk8 = ((kk - 4) & 3) * 4 + lg;
#pragma unroll
            for (int rf = 0; rf < 4; ++rf) {
                int arow = 16 * rf + lr;
                ah[rf] = *(const bfrag*)(ldsP + ((size_t)kk8 * 128 + seg * 64 + arow) * 8);
                al[rf] = *(const bfrag*)(ldsP + ((size_t)(16 + kk8) * 128 + seg * 64 + arow) * 8);
            }
        } else {
            const u16* ab = ldsA + (kk % 3) * 4096;
#pragma unroll
            for (int rf = 0; rf < 4; ++rf) {
                int arow = 16 * rf + lr;
                ah[rf] = *(const bfrag*)(ab + ((size_t)lg * 64 + arow) * 8);
                al[rf] = *(const bfrag*)(ab + ((size_t)(4 + lg) * 64 + arow) * 8);
            }
        }
#pragma unroll
        for (int cf = 0; cf < NCF; ++cf) {
#pragma unroll
            for (int rf = 0; rf < 4; ++rf)
                acc[rf][cf] = __builtin_amdgcn_mfma_f32_16x16x32_bf16(ah[rf], bh[cf], acc[rf][cf], 0, 0, 0);
#pragma unroll
            for (int rf = 0; rf < 4; ++rf)
                acc[rf][cf] = __builtin_amdgcn_mfma_f32_16x16x32_bf16(al[rf], bh[cf], acc[rf][cf], 0, 0, 0);
#pragma unroll
            for (int rf = 0; rf < 4; ++rf)
                acc[rf][cf] = __builtin_amdgcn_mfma_f32_16x16x32_bf16(ah[rf], bl[cf], acc[rf][cf], 0, 0, 0);
        }
    };

    bfrag bhA[NCF], blA[NCF], bhB[NCF], blB[NCF];
    stageA(0, 0);
    loadB(0, bhA, blA);
    stageA(1, 1);

#pragma unroll 1
    for (int kc = 0; kc < NKC; kc += 2) {
        loadB(kc + 1, bhB, blB);
        if constexpr (MODE == 2) { if (kc <= 2) waitv<NB + 1>(); else waitv<NB>(); }
        else waitv<NB + 1>();
        __builtin_amdgcn_s_barrier();
        asm volatile("" ::: "memory");
        if constexpr (MODE == 2) { if (kc + 2 < 4) stageA(kc + 2, (kc + 2) % 3); }
        else                     { if (kc + 2 <= NKC - 1) stageA(kc + 2, (kc + 2) % 3); }
        compute(kc, bhA, blA);

        { int kn = kc + 2; if (kn > NKC - 1) kn = NKC - 1; loadB(kn, bhA, blA); }
        if constexpr (MODE == 2) { if (kc == 0) waitv<NB + 1>(); else waitv<NB>(); }
        else { if (kc == NKC - 2) waitv<NB>(); else waitv<NB + 1>(); }
        __builtin_amdgcn_s_barrier();
        asm volatile("" ::: "memory");
        if constexpr (MODE == 2) { if (kc + 3 < 4) stageA(kc + 3, (kc + 3) % 3); }
        else                     { if (kc + 3 <= NKC - 1) stageA(kc + 3, (kc + 3) % 3); }
        compute(kc + 1, bhB, blB);
    }
}

// ---------------- child epilogue (r11 verbatim) ----------------
template<int NCF, bool LEAF>
__device__ __forceinline__ void child_epilogue(
    f32x4 (&acc)[4][NCF],
    const int* __restrict__ mask,
    const float* __restrict__ b_iou_x, const float* __restrict__ b_f_x,
    const float* __restrict__ b_iou_h, const float* __restrict__ b_f_h,
    float* __restrict__ h, const float* __restrict__ c,
    u16* ldsP, float* ldsC,
    int n0, int lastn, int oBase, int t)
{
    const int l = t & 63, wq = t >> 6, lr = l & 15, lg = l >> 4;
    const int j = 16 * wq + lr;
    float bix = b_iou_x[j], box = b_iou_x[HS + j], bux = b_iou_x[2 * HS + j];
    float bih = b_iou_h[j], boh = b_iou_h[HS + j], buh = b_iou_h[2 * HS + j];
    float bfx = 0.0f, bfh = 0.0f;
    if constexpr (!LEAF) { bfx = b_f_x[j]; bfh = b_f_h[j]; }
#pragma unroll
    for (int rf = 0; rf < 4; ++rf) {
#pragma unroll
        for (int r = 0; r < 4; ++r) {
            int ctr = 16 * rf + 4 * lg + r;
            int n = n0 + ctr;
            if (n >= lastn) continue;
            float m = (float)mask[n];
            float iv = acc[rf][0][r] + m * bix + bih;
            float ov = acc[rf][1][r] + m * box + boh;
            float uv = acc[rf][2][r] + m * bux + buh;
            float cn;
            if constexpr (!LEAF) {
                float fl = acc[rf][3][r] + m * bfx + bfh;
                float fr = acc[rf][4][r] + m * bfx + bfh;
                float cl = c[(size_t)(2 * n + 1) * HS + j];
                float cr = c[(size_t)(2 * n + 2) * HS + j];
                cn = sigf(iv) * tanhfast(uv) + sigf(fl) * cl + sigf(fr) * cr;
            } else {
                cn = sigf(iv) * tanhfast(uv);
            }
            float hn = sigf(ov) * tanhfast(cn);
            h[(size_t)n * HS + j] = hn;
            int o = oBase + ctr;
            int half = o & 1, slot = o >> 1;
            u16 hh = f2bf(hn);
            ldsP[((size_t)(j >> 3) * 128 + half * 64 + slot) * 8 + (j & 7)] = hh;
            ldsP[((size_t)(16 + (j >> 3)) * 128 + half * 64 + slot) * 8 + (j & 7)] = f2bf(hn - bf2f(hh));
            ldsC[o * 129 + j] = cn;
        }
    }
}

// ---------------- parent epilogue (r11 verbatim) ----------------
__device__ __forceinline__ void parent_epilogue(
    f32x4 (&acc)[4][5],
    const int* __restrict__ mask,
    const float* __restrict__ b_iou_x, const float* __restrict__ b_f_x,
    const float* __restrict__ b_iou_h, const float* __restrict__ b_f_h,
    float* __restrict__ h, float* __restrict__ c, u16* __restrict__ hbH,
    const float* ldsC,
    int n0, int lastn, int t)
{
    u16* hbL = hbH + DHB;
    const int l = t & 63, wq = t >> 6, lr = l & 15, lg = l >> 4;
    const int j = 16 * wq + lr;
    float bix = b_iou_x[j], box = b_iou_x[HS + j], bux = b_iou_x[2 * HS + j];
    float bih = b_iou_h[j], boh = b_iou_h[HS + j], buh = b_iou_h[2 * HS + j];
    float bfx = b_f_x[j], bfh = b_f_h[j];
#pragma unroll
    for (int rf = 0; rf < 4; ++rf) {
#pragma unroll
        for (int r = 0; r < 4; ++r) {
            int ctr = 16 * rf + 4 * lg + r;
            int n = n0 + ctr;
            if (n >= lastn) continue;
            float m = (float)mask[n];
            float iv = acc[rf][0][r] + m * bix + bih;
            float ov = acc[rf][1][r] + m * box + boh;
            float uv = acc[rf][2][r] + m * bux + buh;
            float fl = acc[rf][3][r] + m * bfx + bfh;
            float fr = acc[rf][4][r] + m * bfx + bfh;
            float cl = ldsC[(2 * ctr) * 129 + j];
            float cr = ldsC[(2 * ctr + 1) * 129 + j];
            float cn = sigf(iv) * tanhfast(uv) + sigf(fl) * cl + sigf(fr) * cr;
            float hn = sigf(ov) * tanhfast(cn);
            c[(size_t)n * HS + j] = cn;
            h[(size_t)n * HS + j] = hn;
            u16 hh = f2bf(hn);
            hbH[(size_t)n * HS + j] = hh;
            hbL[(size_t)n * HS + j] = f2bf(hn - bf2f(hh));
        }
    }
}

// ---------------- fused (parent, child) level-pair kernel (r11 verbatim) ----------------
template<bool LEAFCH>
__global__ __launch_bounds__(512, 2) void fused_pair(
    const int* __restrict__ x, const int* __restrict__ mask,
    const u16* __restrict__ EH, const u16* __restrict__ zbp,
    const u16* __restrict__ Bint, const u16* __restrict__ Bleaf,
    const float* __restrict__ b_iou_x, const float* __restrict__ b_f_x,
    const float* __restrict__ b_iou_h, const float* __restrict__ b_f_h,
    float* __restrict__ h, float* __restrict__ c, u16* __restrict__ hbH,
    int s0p, int Mp)
{
    __shared__ __align__(16) u16 ldsA[3 * 4096];
    __shared__ __align__(16) u16 ldsP[2 * 16 * 128 * 8];
    __shared__ __align__(16) float ldsC[128 * 129];
    const int t = threadIdx.x;
    const int p0 = s0p + blockIdx.x * 64;
    const int lastp = s0p + Mp;
    const int lastc = 2 * lastp + 1;

    constexpr int CNCF = LEAFCH ? 3 : 5;
    const f32x4 zzz = {0.0f, 0.0f, 0.0f, 0.0f};

    {
        f32x4 acc[4][CNCF];
#pragma unroll
        for (int rf = 0; rf < 4; ++rf)
#pragma unroll
            for (int cf = 0; cf < CNCF; ++cf) acc[rf][cf] = zzz;
        phase_gemm<LEAFCH ? 4 : 12, LEAFCH ? 24 : 40, CNCF, LEAFCH ? 0 : 1>(
            acc, x, mask, EH, zbp, hbH, LEAFCH ? Bleaf : Bint, ldsA, ldsP, 2 * p0 + 1, lastc, t);
        child_epilogue<CNCF, LEAFCH>(acc, mask, b_iou_x, b_f_x, b_iou_h, b_f_h,
                                     h, c, ldsP, ldsC, 2 * p0 + 1, lastc, 0, t);
    }
    __syncthreads();
    {
        f32x4 acc[4][CNCF];
#pragma unroll
        for (int rf = 0; rf < 4; ++rf)
#pragma unroll
            for (int cf = 0; cf < CNCF; ++cf) acc[rf][cf] = zzz;
        phase_gemm<LEAFCH ? 4 : 12, LEAFCH ? 24 : 40, CNCF, LEAFCH ? 0 : 1>(
            acc, x, mask, EH, zbp, hbH, LEAFCH ? Bleaf : Bint, ldsA, ldsP, 2 * p0 + 65, lastc, t);
        child_epilogue<CNCF, LEAFCH>(acc, mask, b_iou_x, b_f_x, b_iou_h, b_f_h,
                                     h, c, ldsP, ldsC, 2 * p0 + 65, lastc, 64, t);
    }
    __syncthreads();
    {
        f32x4 acc[4][5];
#pragma unroll
        for (int rf = 0; rf < 4; ++rf)
#pragma unroll
            for (int cf = 0; cf < 5; ++cf) acc[rf][cf] = zzz;
        phase_gemm<12, 40, 5, 2>(acc, x, mask, EH, zbp, hbH, Bint, ldsA, ldsP, p0, lastp, t);
        parent_epilogue(acc, mask, b_iou_x, b_f_x, b_iou_h, b_f_h,
                        h, c, hbH, ldsC, p0, lastp, t);
    }
}

// ---------------- persistent tail kernel: levels 11..0 ----------------
// Grid: 40 blocks = 8 column-groups (wq) x 5 row-groups (rg).
// B: 120KB LDS-resident (preloaded once).  A: register-resident, 3 segments of
// 8 frags with a 2-buffer pipeline (peak ~16 live frags = 64 VGPR — no spill).
// No barriers / no LDS staging inside a tile.  Grid barrier between levels.
#define TAIL_BLOCKS 40

__device__ __forceinline__ void grid_barrier(u32* ctr, u32 target, int t) {
    __syncthreads();
    if (t == 0) {
        __threadfence();
        __hip_atomic_fetch_add(ctr, 1u, __ATOMIC_RELEASE, __HIP_MEMORY_SCOPE_AGENT);
        while (__hip_atomic_load(ctr, __ATOMIC_ACQUIRE, __HIP_MEMORY_SCOPE_AGENT) < target)
            __builtin_amdgcn_s_sleep(4);
        __threadfence();
    }
    __syncthreads();
}

__global__ __launch_bounds__(512, 2) void tail_kernel(
    const int* __restrict__ x, const int* __restrict__ mask,
    const u16* __restrict__ EH, const u16* __restrict__ zbp,
    const u16* __restrict__ Bint,
    const float* __restrict__ b_iou_x, const float* __restrict__ b_f_x,
    const float* __restrict__ b_iou_h, const float* __restrict__ b_f_h,
    float* __restrict__ h, float* __restrict__ c, u16* __restrict__ hbH,
    u32* __restrict__ bar)
{
    __shared__ __align__(16) u16 ldsB[120 * 512];   // 120 KB: B slice for wq
    const int t = threadIdx.x;
    const int wq = blockIdx.x & 7;
    const int rg = blockIdx.x >> 3;        // 0..4
    const int l = t & 63, w = t >> 6;
    const int lr = l & 15, lg = l >> 4;
    u16* hbL = hbH + DHB;

    // ---- one-time B preload: 120 segments of 1KB ----
    for (int rr = 0; rr < 15; ++rr) {
        int s = rr * 8 + w;                          // 0..119
        int kcq = s / 10, rem = s % 10, cf = rem >> 1, half = rem & 1;
        const u16* src = Bint + ((size_t)((kcq * 40 + wq * 5 + cf) * 2 + half)) * 512 + l * 8;
        *(bfrag*)(ldsB + (size_t)s * 512 + l * 8) = *(const bfrag*)src;
    }
    __syncthreads();

    // per-lane output column (fixed for whole kernel)
    const int j = 16 * wq + lr;
    const float bix = b_iou_x[j], box = b_iou_x[HS + j], bux = b_iou_x[2 * HS + j];
    const float bih = b_iou_h[j], boh = b_iou_h[HS + j], buh = b_iou_h[2 * HS + j];
    const float bfx = b_f_x[j], bfh = b_f_h[j];

    const f32x4 zzz = {0.0f, 0.0f, 0.0f, 0.0f};

#pragma unroll 1
    for (int lvl = 11; lvl >= 0; --lvl) {
        const int s0 = (1 << lvl) - 1, M = 1 << lvl;
        const int lastn = s0 + M;
        const int ntiles = (M + 127) >> 7;
#pragma unroll 1
        for (int tile = rg; tile < ntiles; tile += 5) {
            const int n0 = s0 + tile * 128;
            // lane (lr,lg) owns A row rowA = n0 + 16w + lr, k-slice lg*8..+8 per kc
            int rowA = n0 + 16 * w + lr;
            if (rowA >= lastn) rowA = n0;
            const int mk = mask[rowA];
            const u16* pE = (mk ? EH + (size_t)x[rowA] * HS : zbp) + lg * 8;
            const int dE = mk ? DPLANE : 0;
            const u16* p1 = hbH + (size_t)(2 * rowA + 1) * HS + lg * 8;
            const u16* p2 = hbH + (size_t)(2 * rowA + 2) * HS + lg * 8;

            f32x4 acc[5];
#pragma unroll
            for (int cf = 0; cf < 5; ++cf) acc[cf] = zzz;

            auto compSeg = [&](bfrag (&H)[4], bfrag (&L)[4], int kcBase) {
#pragma unroll
                for (int q = 0; q < 4; ++q) {
                    const u16* bb = ldsB + (size_t)(kcBase + q) * (10 * 512) + l * 8;
#pragma unroll
                    for (int cf = 0; cf < 5; ++cf) {
                        bfrag bh = *(const bfrag*)(bb + (size_t)(2 * cf) * 512);
                        bfrag bl = *(const bfrag*)(bb + (size_t)(2 * cf + 1) * 512);
                        acc[cf] = __builtin_amdgcn_mfma_f32_16x16x32_bf16(H[q], bh, acc[cf], 0, 0, 0);
                        acc[cf] = __builtin_amdgcn_mfma_f32_16x16x32_bf16(L[q], bh, acc[cf], 0, 0, 0);
                        acc[cf] = __builtin_amdgcn_mfma_f32_16x16x32_bf16(H[q], bl, acc[cf], 0, 0, 0);
                    }
                }
            };

            // 3-segment, 2-buffer pipeline: peak 16 live frags (64 VGPR)
            bfrag aH[4], aL[4], bH[4], bL[4];
#pragma unroll
            for (int kc = 0; kc < 4; ++kc) {         // seg E -> buf a
                aH[kc] = *(const bfrag*)(pE + kc * 32);
                aL[kc] = *(const bfrag*)(pE + kc * 32 + dE);
            }
#pragma unroll
            for (int kc = 0; kc < 4; ++kc) {         // seg h-left -> buf b
                bH[kc] = *(const bfrag*)(p1 + kc * 32);
                bL[kc] = *(const bfrag*)(p1 + kc * 32 + DHB);
            }
            compSeg(aH, aL, 0);                      // consume E
#pragma unroll
            for (int kc = 0; kc < 4; ++kc) {         // seg h-right -> buf a (reuse)
                aH[kc] = *(const bfrag*)(p2 + kc * 32);
                aL[kc] = *(const bfrag*)(p2 + kc * 32 + DHB);
            }
            compSeg(bH, bL, 4);                      // consume h-left
            compSeg(aH, aL, 8);                      // consume h-right

            // ---- epilogue: rows n0 + 16w + 4lg + r, column j ----
#pragma unroll
            for (int r = 0; r < 4; ++r) {
                int n = n0 + 16 * w + 4 * lg + r;
                if (n >= lastn) continue;
                float m = (float)mask[n];
                float iv = acc[0][r] + m * bix + bih;
                float ov = acc[1][r] + m * box + boh;
                float uv = acc[2][r] + m * bux + buh;
                float fl = acc[3][r] + m * bfx + bfh;
                float fr = acc[4][r] + m * bfx + bfh;
                float cl = c[(size_t)(2 * n + 1) * HS + j];
                float cr = c[(size_t)(2 * n + 2) * HS + j];
                float cn = sigf(iv) * tanhfast(uv) + sigf(fl) * cl + sigf(fr) * cr;
                float hn = sigf(ov) * tanhfast(cn);
                c[(size_t)n * HS + j] = cn;
                h[(size_t)n * HS + j] = hn;
                u16 hh = f2bf(hn);
                hbH[(size_t)n * HS + j] = hh;
                hbL[(size_t)n * HS + j] = f2bf(hn - bf2f(hh));
            }
        }
        if (lvl > 0) grid_barrier(&bar[11 - lvl], TAIL_BLOCKS, t);
    }
}

extern "C" void kernel_launch(void* const* d_in, const int* in_sizes, int n_in,
                              void* d_out, int out_size, void* d_ws, size_t ws_size,
                              hipStream_t stream)
{
    const int*   x       = (const int*)d_in[0];
    const int*   mask    = (const int*)d_in[1];
    const float* E       = (const float*)d_in[2];
    const float* W_iou   = (const float*)d_in[3];
    const float* b_iou_x = (const float*)d_in[4];
    const float* W_f     = (const float*)d_in[5];
    const float* b_f_x   = (const float*)d_in[6];
    const float* U_iou   = (const float*)d_in[7];
    const float* b_iou_h = (const float*)d_in[8];
    const float* U_f     = (const float*)d_in[9];
    const float* b_f_h   = (const float*)d_in[10];

    float* h = (float*)d_out;
    char* ws = (char*)d_ws;

    u16*   Bint  = (u16*)(ws);                      // 983,040
    u16*   Bleaf = (u16*)(ws + 983040);             // 196,608 -> 1,179,648
    float* zbf   = (float*)(ws + 1179648);          // 512     -> 1,180,160 (barrier ctrs live here)
    u32*   bar   = (u32*)(ws + 1179648);            // zeroed by prep each launch
    u16*   EH    = (u16*)(ws + 1180160);            // 8,192,000  -> 9,372,160
    u16*   EL    = (u16*)(ws + 9372160);            // 8,192,000  -> 17,564,160 (EH + DPLANE)
    u16*   zbp   = (u16*)(ws + 17564160);           // 256        -> 17,564,416
    float* c     = (float*)(ws + 17564416);         // 134,217,216 -> 151,781,632
    u16*   hbH   = (u16*)(ws + 151781632);          // 2 x 67,108,608 -> 285,998,848 (hbL = hbH + DHB)

    prep_kernel<<<PREP_ALL / 256, 256, 0, stream>>>(
        W_iou, W_f, U_iou, U_f, E, Bint, Bleaf, EH, EL, zbp, zbf);

    // fused (parent, child) pairs for the big levels: (16,17), (14,15), (12,13)
    for (int lvl = 16; lvl >= 12; lvl -= 2) {
        int s0p = (1 << lvl) - 1, Mp = 1 << lvl;
        int blocks = (Mp + 63) / 64;
        if (lvl == 16)
            fused_pair<true><<<blocks, 512, 0, stream>>>(
                x, mask, EH, zbp, Bint, Bleaf,
                b_iou_x, b_f_x, b_iou_h, b_f_h, h, c, hbH, s0p, Mp);
        else
            fused_pair<false><<<blocks, 512, 0, stream>>>(
                x, mask, EH, zbp, Bint, Bleaf,
                b_iou_x, b_f_x, b_iou_h, b_f_h, h, c, hbH, s0p, Mp);
    }

    // persistent tail: levels 11..0, B LDS-resident, register-pipelined A
    tail_kernel<<<TAIL_BLOCKS, 512, 0, stream>>>(
        x, mask, EH, zbp, Bint,
        b_iou_x, b_f_x, b_iou_h, b_f_h, h, c, hbH, bar);
}